// Round 1
// baseline (511.302 us; speedup 1.0000x reference)
//
#include <hip/hip_runtime.h>

// ODCMemory.update_samples_memory for MI355X (gfx950)
// Inputs (f32/int32 on device):
//   d_in[0] feature_bank [L,D] f32   d_in[1] label_bank [L] int
//   d_in[2] centroids   [C,D] f32    d_in[3] ind [B] int
//   d_in[4] feature     [B,D] f32
// Output d_out (f32, concatenated): new_bank [L*D] | new_labels [L] | change_ratio [1]

constexpr int Lb  = 500000;
constexpr int Dm  = 256;
constexpr int D4  = 64;      // float4 per row
constexpr int Cc  = 1024;
constexpr int Bb  = 16384;
constexpr float EPSV = 1e-10f;

constexpr int GC = 512;              // classification blocks (32 batch rows each)
constexpr int GM = 1536;             // copy blocks
constexpr int COPY_WAVES = GM * 4;   // one wave handles one bank row per iter

__device__ __forceinline__ float wave_sum64(float v) {
#pragma unroll
  for (int off = 32; off > 0; off >>= 1) v += __shfl_xor(v, off);
  return v;
}

__global__ void k_clear(int* __restrict__ marker, int* __restrict__ count) {
  int i = blockIdx.x * blockDim.x + threadIdx.x;
  const int stride = gridDim.x * blockDim.x;
  for (; i < Lb; i += stride) marker[i] = -1;
  if (blockIdx.x == 0 && threadIdx.x == 0) *count = 0;
}

__global__ void k_mark(const int* __restrict__ ind, int* __restrict__ marker) {
  const int b = blockIdx.x * blockDim.x + threadIdx.x;
  if (b < Bb) atomicMax(&marker[ind[b]], b);
}

// Compute feat_new for batch row gb, distributed as float4 per lane (64 lanes).
__device__ __forceinline__ float4 feat_new_row(const float4* __restrict__ feat4,
                                               const float4* __restrict__ bank4,
                                               int gb, int bankrow, int lane) {
  float4 f = feat4[(size_t)gb * D4 + lane];
  const float ss = wave_sum64(f.x * f.x + f.y * f.y + f.z * f.z + f.w * f.w);
  const float inv1 = 1.0f / (sqrtf(ss) + EPSV);
  const float4 o = bank4[(size_t)bankrow * D4 + lane];
  float4 nw;
  nw.x = 0.5f * o.x + 0.5f * (f.x * inv1);
  nw.y = 0.5f * o.y + 0.5f * (f.y * inv1);
  nw.z = 0.5f * o.z + 0.5f * (f.z * inv1);
  nw.w = 0.5f * o.w + 0.5f * (f.w * inv1);
  const float s2 = wave_sum64(nw.x * nw.x + nw.y * nw.y + nw.z * nw.z + nw.w * nw.w);
  const float inv2 = 1.0f / (sqrtf(s2) + EPSV);
  nw.x *= inv2; nw.y *= inv2; nw.z *= inv2; nw.w *= inv2;
  return nw;
}

__global__ __launch_bounds__(256)
void k_main(const float4* __restrict__ bank4, const float4* __restrict__ cent4,
            const float4* __restrict__ feat4, const int* __restrict__ ind,
            const int* __restrict__ label_bank, const int* __restrict__ marker,
            int* __restrict__ newlabel, int* __restrict__ count,
            float4* __restrict__ out4) {
  __shared__ float fs[32][Dm];     // 32 KB: feat_new tile
  __shared__ float redv[32][4];
  __shared__ int   redc[32][4];
  const int tid = threadIdx.x;
  const int lane = tid & 63;
  const int wv = tid >> 6;

  if (blockIdx.x < GC) {
    // ---- classification role: 32 batch rows ----
    const int b0 = (int)blockIdx.x * 32;
#pragma unroll
    for (int k = 0; k < 8; ++k) {
      const int b = wv * 8 + k;
      const int gb = b0 + b;
      const float4 nw = feat_new_row(feat4, bank4, gb, ind[gb], lane);
      *reinterpret_cast<float4*>(&fs[b][lane * 4]) = nw;
    }
    __syncthreads();

    float acc[4][32];
#pragma unroll
    for (int ci = 0; ci < 4; ++ci)
#pragma unroll
      for (int b = 0; b < 32; ++b) acc[ci][b] = 0.0f;

    const float4* cp0 = cent4 + (size_t)(tid      ) * D4;
    const float4* cp1 = cent4 + (size_t)(tid + 256) * D4;
    const float4* cp2 = cent4 + (size_t)(tid + 512) * D4;
    const float4* cp3 = cent4 + (size_t)(tid + 768) * D4;

    for (int d4 = 0; d4 < D4; ++d4) {
      const float4 c0 = cp0[d4];
      const float4 c1 = cp1[d4];
      const float4 c2 = cp2[d4];
      const float4 c3 = cp3[d4];
#pragma unroll
      for (int b = 0; b < 32; ++b) {
        const float4 f = *reinterpret_cast<const float4*>(&fs[b][d4 * 4]);
        acc[0][b] = fmaf(c0.w, f.w, fmaf(c0.z, f.z, fmaf(c0.y, f.y, fmaf(c0.x, f.x, acc[0][b]))));
        acc[1][b] = fmaf(c1.w, f.w, fmaf(c1.z, f.z, fmaf(c1.y, f.y, fmaf(c1.x, f.x, acc[1][b]))));
        acc[2][b] = fmaf(c2.w, f.w, fmaf(c2.z, f.z, fmaf(c2.y, f.y, fmaf(c2.x, f.x, acc[2][b]))));
        acc[3][b] = fmaf(c3.w, f.w, fmaf(c3.z, f.z, fmaf(c3.y, f.y, fmaf(c3.x, f.x, acc[3][b]))));
      }
    }

    // argmax per batch row; ties -> smallest centroid index (numpy semantics)
#pragma unroll
    for (int b = 0; b < 32; ++b) {
      float v = acc[0][b]; int c = tid;
      if (acc[1][b] > v) { v = acc[1][b]; c = tid + 256; }
      if (acc[2][b] > v) { v = acc[2][b]; c = tid + 512; }
      if (acc[3][b] > v) { v = acc[3][b]; c = tid + 768; }
#pragma unroll
      for (int off = 32; off > 0; off >>= 1) {
        const float ov = __shfl_xor(v, off);
        const int   oc = __shfl_xor(c, off);
        if (ov > v || (ov == v && oc < c)) { v = ov; c = oc; }
      }
      if (lane == 0) { redv[b][wv] = v; redc[b][wv] = c; }
    }
    __syncthreads();
    if (tid < 32) {
      const int b = tid;
      float v = redv[b][0]; int c = redc[b][0];
#pragma unroll
      for (int w = 1; w < 4; ++w) {
        const float ov = redv[b][w]; const int oc = redc[b][w];
        if (ov > v || (ov == v && oc < c)) { v = ov; c = oc; }
      }
      const int gb = b0 + b;
      newlabel[gb] = c;
      if (c != label_bank[ind[gb]]) atomicAdd(count, 1);
    }
  } else {
    // ---- copy role: one wave per bank row (1 KB), winners recompute feat_new ----
    const int wid = ((int)blockIdx.x - GC) * 4 + wv;
    for (int row = wid; row < Lb; row += COPY_WAVES) {
      const int m = marker[row];  // wave-uniform
      const float4* src = bank4 + (size_t)row * D4;
      float4*       dst = out4  + (size_t)row * D4;
      if (m < 0) {
        dst[lane] = src[lane];
      } else {
        dst[lane] = feat_new_row(feat4, bank4, m, row, lane);
      }
    }
  }
}

__global__ void k_labels(const int* __restrict__ marker, const int* __restrict__ newlabel,
                         const int* __restrict__ label_bank, const int* __restrict__ count,
                         float* __restrict__ out_lab, float* __restrict__ out_ratio) {
  int i = blockIdx.x * blockDim.x + threadIdx.x;
  const int stride = gridDim.x * blockDim.x;
  for (; i < Lb; i += stride) {
    const int m = marker[i];
    out_lab[i] = (float)(m >= 0 ? newlabel[m] : label_bank[i]);
  }
  if (blockIdx.x == 0 && threadIdx.x == 0)
    *out_ratio = (float)(*count) / (float)Bb;
}

extern "C" void kernel_launch(void* const* d_in, const int* in_sizes, int n_in,
                              void* d_out, int out_size, void* d_ws, size_t ws_size,
                              hipStream_t stream) {
  const float* bank       = (const float*)d_in[0];
  const int*   label_bank = (const int*)  d_in[1];
  const float* cent       = (const float*)d_in[2];
  const int*   ind        = (const int*)  d_in[3];
  const float* feat       = (const float*)d_in[4];
  float* out = (float*)d_out;

  int* marker   = (int*)d_ws;          // [Lb]
  int* newlabel = marker + Lb;         // [Bb]
  int* count    = newlabel + Bb;       // [1]

  float* out_lab   = out + (size_t)Lb * Dm;
  float* out_ratio = out_lab + Lb;

  k_clear<<<1954, 256, 0, stream>>>(marker, count);
  k_mark<<<Bb / 256, 256, 0, stream>>>(ind, marker);
  k_main<<<GC + GM, 256, 0, stream>>>((const float4*)bank, (const float4*)cent,
                                      (const float4*)feat, ind, label_bank, marker,
                                      newlabel, count, (float4*)out);
  k_labels<<<1954, 256, 0, stream>>>(marker, newlabel, label_bank, count,
                                     out_lab, out_ratio);
}

// Round 2
// 499.006 us; speedup vs baseline: 1.0246x; 1.0246x over previous
//
#include <hip/hip_runtime.h>
#include <math.h>

// ODCMemory.update_samples_memory for MI355X (gfx950)
// d_in[0] feature_bank [L,D] f32   d_in[1] label_bank [L] int32
// d_in[2] centroids   [C,D] f32    d_in[3] ind [B] int32
// d_in[4] feature     [B,D] f32
// d_out f32: new_bank [L*D] | new_labels [L] | change_ratio [1]

constexpr int Lb  = 500000;
constexpr int Dm  = 256;
constexpr int D4  = 64;      // float4 per row
constexpr int Cc  = 1024;
constexpr int Bb  = 16384;
constexpr float EPSV = 1e-10f;

constexpr int GC = 512;               // classify blocks (32 batch rows each)
constexpr int GM = 1536;              // copy blocks
constexpr int GPOST = 1954;

__device__ __forceinline__ float wave_sum64(float v) {
#pragma unroll
  for (int off = 32; off > 0; off >>= 1) v += __shfl_xor(v, off);
  return v;
}

// feat_new for batch row gb against bank row bankrow; lane holds float4 slice.
__device__ __forceinline__ float4 feat_new_row(const float4* __restrict__ feat4,
                                               const float4* __restrict__ bank4,
                                               int gb, int bankrow, int lane) {
  float4 f = feat4[(size_t)gb * D4 + lane];
  const float ss = wave_sum64(f.x * f.x + f.y * f.y + f.z * f.z + f.w * f.w);
  const float inv1 = 1.0f / (sqrtf(ss) + EPSV);
  const float4 o = bank4[(size_t)bankrow * D4 + lane];
  float4 nw;
  nw.x = 0.5f * o.x + 0.5f * (f.x * inv1);
  nw.y = 0.5f * o.y + 0.5f * (f.y * inv1);
  nw.z = 0.5f * o.z + 0.5f * (f.z * inv1);
  nw.w = 0.5f * o.w + 0.5f * (f.w * inv1);
  const float s2 = wave_sum64(nw.x * nw.x + nw.y * nw.y + nw.z * nw.z + nw.w * nw.w);
  const float inv2 = 1.0f / (sqrtf(s2) + EPSV);
  nw.x *= inv2; nw.y *= inv2; nw.z *= inv2; nw.w *= inv2;
  return nw;
}

// clear marker + count, transpose centroids into centT [D][C]
__global__ void k_pre(int* __restrict__ marker, int* __restrict__ count,
                      const float* __restrict__ cent, float* __restrict__ centT) {
  const int t = blockIdx.x * blockDim.x + threadIdx.x;
  const int stride = gridDim.x * blockDim.x;
  for (int i = t; i < Lb; i += stride) marker[i] = -1;
  if (t < Cc * Dm) {
    const int d = t >> 10, c = t & (Cc - 1);
    centT[t] = cent[c * Dm + d];      // coalesced write, strided read (L2-resident)
  }
  if (t == 0) *count = 0;
}

__global__ void k_mark(const int* __restrict__ ind, int* __restrict__ marker) {
  const int b = blockIdx.x * blockDim.x + threadIdx.x;
  if (b < Bb) atomicMax(&marker[ind[b]], b);
}

__global__ __launch_bounds__(256, 4)
void k_main(const float4* __restrict__ bank4, const float4* __restrict__ centT4,
            const float4* __restrict__ feat4, const int* __restrict__ ind,
            const int* __restrict__ label_bank,
            int* __restrict__ newlabel, int* __restrict__ count,
            float4* __restrict__ out4) {
  const int tid  = threadIdx.x;
  const int lane = tid & 63;
  const int wv   = tid >> 6;
  const int bid  = blockIdx.x;

  if (bid < GC) {
    // ---------- classification: 32 batch rows; wave wv owns rows wv*8..wv*8+7
    __shared__ float fs[32][Dm];     // 32 KB feat_new tile
    const int b0 = bid * 32;
#pragma unroll
    for (int k = 0; k < 8; ++k) {
      const int b = wv * 8 + k;
      const int gb = b0 + b;
      const float4 nw = feat_new_row(feat4, bank4, gb, ind[gb], lane);
      *reinterpret_cast<float4*>(&fs[b][lane * 4]) = nw;
    }
    __syncthreads();

    float bestv[8]; int bestc[8];
#pragma unroll
    for (int b = 0; b < 8; ++b) { bestv[b] = -INFINITY; bestc[b] = 0; }

    for (int j = 0; j < 4; ++j) {           // centroid group: c = 256*j + 4*lane + k
      float4 acc[8];
#pragma unroll
      for (int b = 0; b < 8; ++b) acc[b] = make_float4(0.f, 0.f, 0.f, 0.f);
      const float4* cp = centT4 + j * 64 + lane;   // centT4[d*256 + j*64+lane]

      for (int d4 = 0; d4 < D4; ++d4) {
        float4 f[8];
#pragma unroll
        for (int b = 0; b < 8; ++b)
          f[b] = *reinterpret_cast<const float4*>(&fs[wv * 8 + b][d4 * 4]); // broadcast
#pragma unroll
        for (int dd = 0; dd < 4; ++dd) {
          const float4 cv = cp[(size_t)(d4 * 4 + dd) * 256];  // coalesced 1KB/wave
#pragma unroll
          for (int b = 0; b < 8; ++b) {
            const float fv = (dd == 0) ? f[b].x : (dd == 1) ? f[b].y : (dd == 2) ? f[b].z : f[b].w;
            acc[b].x = fmaf(cv.x, fv, acc[b].x);
            acc[b].y = fmaf(cv.y, fv, acc[b].y);
            acc[b].z = fmaf(cv.z, fv, acc[b].z);
            acc[b].w = fmaf(cv.w, fv, acc[b].w);
          }
        }
      }
      // merge (ascending index order; strict > keeps smallest index on ties)
      const int cbase = j * 256 + lane * 4;
#pragma unroll
      for (int b = 0; b < 8; ++b) {
        if (acc[b].x > bestv[b]) { bestv[b] = acc[b].x; bestc[b] = cbase; }
        if (acc[b].y > bestv[b]) { bestv[b] = acc[b].y; bestc[b] = cbase + 1; }
        if (acc[b].z > bestv[b]) { bestv[b] = acc[b].z; bestc[b] = cbase + 2; }
        if (acc[b].w > bestv[b]) { bestv[b] = acc[b].w; bestc[b] = cbase + 3; }
      }
    }

    // cross-lane argmax per batch row (tie -> smallest centroid index)
#pragma unroll
    for (int b = 0; b < 8; ++b) {
      float v = bestv[b]; int c = bestc[b];
#pragma unroll
      for (int off = 32; off > 0; off >>= 1) {
        const float ov = __shfl_xor(v, off);
        const int   oc = __shfl_xor(c, off);
        if (ov > v || (ov == v && oc < c)) { v = ov; c = oc; }
      }
      if (lane == 0) {
        const int gb = b0 + wv * 8 + b;
        newlabel[gb] = c;
        if (c != label_bank[ind[gb]]) atomicAdd(count, 1);
      }
    }
  } else {
    // ---------- pure streaming copy of the whole bank (no marker logic)
    const size_t stride = (size_t)GM * 256;
    const size_t n4 = (size_t)Lb * D4;
    size_t i = (size_t)(bid - GC) * 256 + tid;
    for (; i + 3 * stride < n4; i += 4 * stride) {
      const float4 a = bank4[i];
      const float4 b = bank4[i + stride];
      const float4 c = bank4[i + 2 * stride];
      const float4 d = bank4[i + 3 * stride];
      out4[i] = a; out4[i + stride] = b; out4[i + 2 * stride] = c; out4[i + 3 * stride] = d;
    }
    for (; i < n4; i += stride) out4[i] = bank4[i];
  }
}

// overwrite winner rows (recompute feat_new), fill labels, write ratio
__global__ void k_post(const float4* __restrict__ bank4, const float4* __restrict__ feat4,
                       const int* __restrict__ ind, const int* __restrict__ marker,
                       const int* __restrict__ newlabel, const int* __restrict__ label_bank,
                       const int* __restrict__ count,
                       float4* __restrict__ out4, float* __restrict__ out_lab,
                       float* __restrict__ out_ratio) {
  const int tid  = threadIdx.x;
  const int lane = tid & 63;
  const int wv   = tid >> 6;
  const int t = blockIdx.x * blockDim.x + tid;
  const int stride = gridDim.x * blockDim.x;

  // labels
  for (int i = t; i < Lb; i += stride) {
    const int m = marker[i];
    out_lab[i] = (float)(m >= 0 ? newlabel[m] : label_bank[i]);
  }
  // winner feature rows
  const int gw = blockIdx.x * 4 + wv;
  const int nwaves = GPOST * 4;
  for (int b = gw; b < Bb; b += nwaves) {
    const int r = ind[b];
    if (marker[r] == b) {
      out4[(size_t)r * D4 + lane] = feat_new_row(feat4, bank4, b, r, lane);
    }
  }
  if (t == 0) *out_ratio = (float)(*count) / (float)Bb;
}

extern "C" void kernel_launch(void* const* d_in, const int* in_sizes, int n_in,
                              void* d_out, int out_size, void* d_ws, size_t ws_size,
                              hipStream_t stream) {
  const float* bank       = (const float*)d_in[0];
  const int*   label_bank = (const int*)  d_in[1];
  const float* cent       = (const float*)d_in[2];
  const int*   ind        = (const int*)  d_in[3];
  const float* feat       = (const float*)d_in[4];
  float* out = (float*)d_out;

  int*   marker   = (int*)d_ws;                 // [Lb]
  int*   newlabel = marker + Lb;                // [Bb]
  int*   count    = newlabel + Bb;              // [1]
  float* centT    = (float*)(count + 1);        // [Dm*Cc] = 1 MB

  float* out_lab   = out + (size_t)Lb * Dm;
  float* out_ratio = out_lab + Lb;

  k_pre <<<GPOST, 256, 0, stream>>>(marker, count, cent, centT);
  k_mark<<<Bb / 256, 256, 0, stream>>>(ind, marker);
  k_main<<<GC + GM, 256, 0, stream>>>((const float4*)bank, (const float4*)centT,
                                      (const float4*)feat, ind, label_bank,
                                      newlabel, count, (float4*)out);
  k_post<<<GPOST, 256, 0, stream>>>((const float4*)bank, (const float4*)feat,
                                    ind, marker, newlabel, label_bank, count,
                                    (float4*)out, out_lab, out_ratio);
}

// Round 4
// 391.674 us; speedup vs baseline: 1.3054x; 1.2740x over previous
//
#include <hip/hip_runtime.h>
#include <math.h>

// ODCMemory.update_samples_memory for MI355X (gfx950)
// d_in[0] feature_bank [L,D] f32   d_in[1] label_bank [L] int32
// d_in[2] centroids   [C,D] f32    d_in[3] ind [B] int32
// d_in[4] feature     [B,D] f32
// d_out f32: new_bank [L*D] | new_labels [L] | change_ratio [1]

constexpr int Lb = 500000;
constexpr int Dm = 256;
constexpr int D4 = 64;          // float4 per row
constexpr int Cc = 1024;
constexpr int Bb = 16384;
constexpr float EPSV = 1e-10f;

constexpr int ROWS  = 16;       // batch rows per classify block
constexpr int GCLS  = Bb / ROWS;        // 1024 classify blocks
constexpr int GCPY  = 1536;             // copy blocks
constexpr int GMAIN = GCLS + GCPY;      // 2560 (period-5 interleave: 2 cls : 3 cpy)
constexpr int GMARK = 64;               // marking blocks (tail of k_main)
constexpr int GPRE  = 1024;
constexpr int GPOST = 1024;

typedef float vfloat4 __attribute__((ext_vector_type(4)));  // native vec for NT stores

__device__ __forceinline__ float wave_sum64(float v) {
#pragma unroll
  for (int off = 32; off > 0; off >>= 1) v += __shfl_xor(v, off);
  return v;
}

// momentum-normalized feature for batch row gb vs bank row bankrow (lane = float4 slice)
__device__ __forceinline__ float4 feat_new_row(const float4* __restrict__ feat4,
                                               const float4* __restrict__ bank4,
                                               int gb, int bankrow, int lane) {
  float4 f = feat4[(size_t)gb * D4 + lane];
  const float ss = wave_sum64(f.x * f.x + f.y * f.y + f.z * f.z + f.w * f.w);
  const float inv1 = 1.0f / (sqrtf(ss) + EPSV);
  const float4 o = bank4[(size_t)bankrow * D4 + lane];
  float4 nw;
  nw.x = 0.5f * o.x + 0.5f * (f.x * inv1);
  nw.y = 0.5f * o.y + 0.5f * (f.y * inv1);
  nw.z = 0.5f * o.z + 0.5f * (f.z * inv1);
  nw.w = 0.5f * o.w + 0.5f * (f.w * inv1);
  const float s2 = wave_sum64(nw.x * nw.x + nw.y * nw.y + nw.z * nw.z + nw.w * nw.w);
  const float inv2 = 1.0f / (sqrtf(s2) + EPSV);
  nw.x *= inv2; nw.y *= inv2; nw.z *= inv2; nw.w *= inv2;
  return nw;
}

// marker clear + count clear + centroid transpose + feat_new precompute
__global__ __launch_bounds__(256)
void k_pre(const float4* __restrict__ feat4, const float4* __restrict__ bank4,
           const int* __restrict__ ind, const float* __restrict__ cent,
           float* __restrict__ centT, float4* __restrict__ fnew4,
           int* __restrict__ marker, int* __restrict__ count) {
  const int tid = threadIdx.x, lane = tid & 63, wv = tid >> 6;
  const int t = blockIdx.x * 256 + tid;
  const int stride = GPRE * 256;
  for (int i = t; i < Lb; i += stride) marker[i] = -1;
  for (int i = t; i < Cc * Dm; i += stride) {
    const int d = i >> 10, c = i & (Cc - 1);
    centT[i] = cent[c * Dm + d];          // centT[d][c]
  }
  if (t == 0) *count = 0;
  const int w = blockIdx.x * 4 + wv;      // 4096 waves, 4 rows each
  for (int b = w; b < Bb; b += GPRE * 4)
    fnew4[(size_t)b * D4 + lane] = feat_new_row(feat4, bank4, b, ind[b], lane);
}

__global__ __launch_bounds__(256, 4)
void k_main(const float4* __restrict__ bank4, const float4* __restrict__ centT4,
            const float4* __restrict__ fnew4, const int* __restrict__ ind,
            const int* __restrict__ label_bank, int* __restrict__ marker,
            int* __restrict__ newlabel, int* __restrict__ count,
            float4* __restrict__ out4) {
  const int tid  = threadIdx.x;
  const int lane = tid & 63;
  const int wv   = tid >> 6;
  const int bid  = blockIdx.x;

  if (bid >= GMAIN) {
    // ---- marking: last-occurrence-wins via atomicMax ----
    const int b = (bid - GMAIN) * 256 + tid;
    if (b < Bb) atomicMax(&marker[ind[b]], b);
    return;
  }

  const int r5 = bid % 5;
  if (r5 < 2) {
    // ---- classify: 16 batch rows, all 1024 centroids (wave wv owns cents wv*256..) ----
    __shared__ float redv[ROWS][4];
    __shared__ int   redc[ROWS][4];
    const int cls = (bid / 5) * 2 + r5;           // 0..1023
    const int b0  = cls * ROWS;
    const int c0  = (wv * 64 + lane) * 4;         // this thread's 4 centroids
    const float4* __restrict__ cvp = centT4 + wv * 64 + lane;  // [d][c/4]
    const float4* __restrict__ fB  = fnew4 + (size_t)b0 * D4;  // uniform base

    float4 acc[ROWS];
#pragma unroll
    for (int r = 0; r < ROWS; ++r) acc[r] = make_float4(0.f, 0.f, 0.f, 0.f);

#pragma unroll 2
    for (int d4 = 0; d4 < D4; ++d4) {
      const float4 cv0 = cvp[(size_t)(d4 * 4 + 0) * 256];
      const float4 cv1 = cvp[(size_t)(d4 * 4 + 1) * 256];
      const float4 cv2 = cvp[(size_t)(d4 * 4 + 2) * 256];
      const float4 cv3 = cvp[(size_t)(d4 * 4 + 3) * 256];
#pragma unroll
      for (int r = 0; r < ROWS; ++r) {
        const float4 f = fB[(size_t)r * D4 + d4];   // wave-uniform -> s_load
        acc[r].x = fmaf(cv0.x, f.x, acc[r].x);
        acc[r].y = fmaf(cv0.y, f.x, acc[r].y);
        acc[r].z = fmaf(cv0.z, f.x, acc[r].z);
        acc[r].w = fmaf(cv0.w, f.x, acc[r].w);
        acc[r].x = fmaf(cv1.x, f.y, acc[r].x);
        acc[r].y = fmaf(cv1.y, f.y, acc[r].y);
        acc[r].z = fmaf(cv1.z, f.y, acc[r].z);
        acc[r].w = fmaf(cv1.w, f.y, acc[r].w);
        acc[r].x = fmaf(cv2.x, f.z, acc[r].x);
        acc[r].y = fmaf(cv2.y, f.z, acc[r].y);
        acc[r].z = fmaf(cv2.z, f.z, acc[r].z);
        acc[r].w = fmaf(cv2.w, f.z, acc[r].w);
        acc[r].x = fmaf(cv3.x, f.w, acc[r].x);
        acc[r].y = fmaf(cv3.y, f.w, acc[r].y);
        acc[r].z = fmaf(cv3.z, f.w, acc[r].z);
        acc[r].w = fmaf(cv3.w, f.w, acc[r].w);
      }
    }

    // per-row argmax: within-thread (ascending index, strict >), cross-lane, cross-wave
#pragma unroll
    for (int r = 0; r < ROWS; ++r) {
      float v = acc[r].x; int c = c0;
      if (acc[r].y > v) { v = acc[r].y; c = c0 + 1; }
      if (acc[r].z > v) { v = acc[r].z; c = c0 + 2; }
      if (acc[r].w > v) { v = acc[r].w; c = c0 + 3; }
#pragma unroll
      for (int off = 32; off > 0; off >>= 1) {
        const float ov = __shfl_xor(v, off);
        const int   oc = __shfl_xor(c, off);
        if (ov > v || (ov == v && oc < c)) { v = ov; c = oc; }
      }
      if (lane == 0) { redv[r][wv] = v; redc[r][wv] = c; }
    }
    __syncthreads();
    if (tid < ROWS) {
      const int r = tid;
      float v = redv[r][0]; int c = redc[r][0];
#pragma unroll
      for (int w = 1; w < 4; ++w) {
        const float ov = redv[r][w]; const int oc = redc[r][w];
        if (ov > v || (ov == v && oc < c)) { v = ov; c = oc; }
      }
      const int gb = b0 + r;
      newlabel[gb] = c;
      if (c != label_bank[ind[gb]]) atomicAdd(count, 1);
    }
  } else {
    // ---- streaming copy of the whole bank; nontemporal stores ----
    const int cpy = (bid / 5) * 3 + (r5 - 2);     // 0..1535
    const size_t stride = (size_t)GCPY * 256;
    const size_t n4 = (size_t)Lb * D4;
    const vfloat4* __restrict__ src = (const vfloat4*)bank4;
    vfloat4* __restrict__ dst = (vfloat4*)out4;
    size_t i = (size_t)cpy * 256 + tid;
    for (; i + 3 * stride < n4; i += 4 * stride) {
      const vfloat4 a = src[i];
      const vfloat4 b = src[i + stride];
      const vfloat4 c = src[i + 2 * stride];
      const vfloat4 d = src[i + 3 * stride];
      __builtin_nontemporal_store(a, &dst[i]);
      __builtin_nontemporal_store(b, &dst[i + stride]);
      __builtin_nontemporal_store(c, &dst[i + 2 * stride]);
      __builtin_nontemporal_store(d, &dst[i + 3 * stride]);
    }
    for (; i < n4; i += stride) __builtin_nontemporal_store(src[i], &dst[i]);
  }
}

// winner rows from fnew, labels, ratio
__global__ __launch_bounds__(256)
void k_post(const float4* __restrict__ fnew4, const int* __restrict__ ind,
            const int* __restrict__ marker, const int* __restrict__ newlabel,
            const int* __restrict__ label_bank, const int* __restrict__ count,
            float4* __restrict__ out4, float* __restrict__ out_lab,
            float* __restrict__ out_ratio) {
  const int tid = threadIdx.x, lane = tid & 63, wv = tid >> 6;
  const int t = blockIdx.x * 256 + tid;
  const int stride = GPOST * 256;
  for (int i = t; i < Lb; i += stride) {
    const int m = marker[i];
    out_lab[i] = (float)(m >= 0 ? newlabel[m] : label_bank[i]);
  }
  const int w = blockIdx.x * 4 + wv;
  for (int b = w; b < Bb; b += GPOST * 4) {
    const int r = ind[b];
    if (marker[r] == b) out4[(size_t)r * D4 + lane] = fnew4[(size_t)b * D4 + lane];
  }
  if (t == 0) *out_ratio = (float)(*count) / (float)Bb;
}

extern "C" void kernel_launch(void* const* d_in, const int* in_sizes, int n_in,
                              void* d_out, int out_size, void* d_ws, size_t ws_size,
                              hipStream_t stream) {
  const float* bank       = (const float*)d_in[0];
  const int*   label_bank = (const int*)  d_in[1];
  const float* cent       = (const float*)d_in[2];
  const int*   ind        = (const int*)  d_in[3];
  const float* feat       = (const float*)d_in[4];
  float* out = (float*)d_out;

  int*   marker   = (int*)d_ws;                  // [Lb]
  int*   newlabel = marker + Lb;                 // [Bb]
  int*   count    = newlabel + Bb;               // [1]
  float* centT    = (float*)(count + 1);         // [Dm*Cc]  1 MB
  float* fnew     = centT + (size_t)Dm * Cc;     // [Bb*Dm] 16 MB

  float* out_lab   = out + (size_t)Lb * Dm;
  float* out_ratio = out_lab + Lb;

  k_pre <<<GPRE, 256, 0, stream>>>((const float4*)feat, (const float4*)bank, ind,
                                   cent, centT, (float4*)fnew, marker, count);
  k_main<<<GMAIN + GMARK, 256, 0, stream>>>((const float4*)bank, (const float4*)centT,
                                            (const float4*)fnew, ind, label_bank,
                                            marker, newlabel, count, (float4*)out);
  k_post<<<GPOST, 256, 0, stream>>>((const float4*)fnew, ind, marker, newlabel,
                                    label_bank, count, (float4*)out, out_lab, out_ratio);
}

// Round 5
// 286.449 us; speedup vs baseline: 1.7850x; 1.3673x over previous
//
#include <hip/hip_runtime.h>
#include <math.h>

// ODCMemory.update_samples_memory for MI355X (gfx950)
// d_in[0] feature_bank [L,D] f32   d_in[1] label_bank [L] int32
// d_in[2] centroids   [C,D] f32    d_in[3] ind [B] int32
// d_in[4] feature     [B,D] f32
// d_out f32: new_bank [L*D] | new_labels [L] | change_ratio [1]

constexpr int Lb = 500000;
constexpr int Dm = 256;
constexpr int D4 = 64;          // float4 per row
constexpr int Cc = 1024;
constexpr int Bb = 16384;
constexpr float EPSV = 1e-10f;

constexpr int ROWS  = 8;                // batch rows per classify block
constexpr int GCLS  = Bb / ROWS;        // 2048 classify blocks
constexpr int GCPY  = 2048;             // copy blocks
constexpr int GMAIN = GCLS + GCPY;      // 4096, interleaved 1:1 by bid&1
constexpr int GMARK = Bb / 256;         // 64 marking blocks (tail)
constexpr int GPRE  = 1024;
constexpr int GPOST = 1024;

typedef float vfloat4 __attribute__((ext_vector_type(4)));  // native vec for NT stores

__device__ __forceinline__ float wave_sum64(float v) {
#pragma unroll
  for (int off = 32; off > 0; off >>= 1) v += __shfl_xor(v, off);
  return v;
}

// momentum-normalized feature for batch row gb vs bank row bankrow (lane = float4 slice)
__device__ __forceinline__ float4 feat_new_row(const float4* __restrict__ feat4,
                                               const float4* __restrict__ bank4,
                                               int gb, int bankrow, int lane) {
  float4 f = feat4[(size_t)gb * D4 + lane];
  const float ss = wave_sum64(f.x * f.x + f.y * f.y + f.z * f.z + f.w * f.w);
  const float inv1 = 1.0f / (sqrtf(ss) + EPSV);
  const float4 o = bank4[(size_t)bankrow * D4 + lane];
  float4 nw;
  nw.x = 0.5f * o.x + 0.5f * (f.x * inv1);
  nw.y = 0.5f * o.y + 0.5f * (f.y * inv1);
  nw.z = 0.5f * o.z + 0.5f * (f.z * inv1);
  nw.w = 0.5f * o.w + 0.5f * (f.w * inv1);
  const float s2 = wave_sum64(nw.x * nw.x + nw.y * nw.y + nw.z * nw.z + nw.w * nw.w);
  const float inv2 = 1.0f / (sqrtf(s2) + EPSV);
  nw.x *= inv2; nw.y *= inv2; nw.z *= inv2; nw.w *= inv2;
  return nw;
}

// marker clear + count clear + centroid transpose + feat_new precompute
__global__ __launch_bounds__(256)
void k_pre(const float4* __restrict__ feat4, const float4* __restrict__ bank4,
           const int* __restrict__ ind, const float* __restrict__ cent,
           float* __restrict__ centT, float4* __restrict__ fnew4,
           int* __restrict__ marker, int* __restrict__ count) {
  const int tid = threadIdx.x, lane = tid & 63, wv = tid >> 6;
  const int t = blockIdx.x * 256 + tid;
  const int stride = GPRE * 256;
  for (int i = t; i < Lb; i += stride) marker[i] = -1;
  for (int i = t; i < Cc * Dm; i += stride) {
    const int d = i >> 10, c = i & (Cc - 1);
    centT[i] = cent[c * Dm + d];          // centT[d][c]; coalesced write
  }
  if (t == 0) *count = 0;
  const int w = blockIdx.x * 4 + wv;      // 4096 waves, 4 rows each
  for (int b = w; b < Bb; b += GPRE * 4)
    fnew4[(size_t)b * D4 + lane] = feat_new_row(feat4, bank4, b, ind[b], lane);
}

__global__ __launch_bounds__(256, 4)
void k_main(const float4* __restrict__ bank4, const float4* __restrict__ centT4,
            const float4* __restrict__ fnew4, const int* __restrict__ ind,
            const int* __restrict__ label_bank, int* __restrict__ marker,
            int* __restrict__ newlabel, int* __restrict__ count,
            float4* __restrict__ out4) {
  const int tid  = threadIdx.x;
  const int lane = tid & 63;
  const int wv   = tid >> 6;
  const int bid  = blockIdx.x;

  if (bid >= GMAIN) {
    // ---- marking: last-occurrence-wins via atomicMax ----
    const int b = (bid - GMAIN) * 256 + tid;
    if (b < Bb) atomicMax(&marker[ind[b]], b);
    return;
  }

  if ((bid & 1) == 0) {
    // ---- classify: 8 batch rows vs all 1024 centroids; thread owns 4 cents ----
    __shared__ float4 fs[ROWS][D4];      // 8 KB feat tile
    __shared__ float  redv[ROWS][4];
    __shared__ int    redc[ROWS][4];
    const int cls = bid >> 1;            // 0..2047
    const int b0  = cls * ROWS;
    const int c0  = tid * 4;             // this thread's 4 centroids

    for (int k = tid; k < ROWS * D4; k += 256)
      ((float4*)fs)[k] = fnew4[(size_t)b0 * D4 + k];
    __syncthreads();

    float4 acc[ROWS];
#pragma unroll
    for (int r = 0; r < ROWS; ++r) acc[r] = make_float4(0.f, 0.f, 0.f, 0.f);

    const float4* __restrict__ cvp = centT4 + tid;   // centT4[d*256 + tid]

    for (int d4 = 0; d4 < D4; ++d4) {
      const float4 cv0 = cvp[(size_t)(d4 * 4 + 0) * 256];   // coalesced 1KB/wave
      const float4 cv1 = cvp[(size_t)(d4 * 4 + 1) * 256];
      const float4 cv2 = cvp[(size_t)(d4 * 4 + 2) * 256];
      const float4 cv3 = cvp[(size_t)(d4 * 4 + 3) * 256];
#pragma unroll
      for (int r = 0; r < ROWS; ++r) {
        const float4 f = fs[r][d4];                         // LDS broadcast
        acc[r].x = fmaf(cv0.x, f.x, acc[r].x);
        acc[r].y = fmaf(cv0.y, f.x, acc[r].y);
        acc[r].z = fmaf(cv0.z, f.x, acc[r].z);
        acc[r].w = fmaf(cv0.w, f.x, acc[r].w);
        acc[r].x = fmaf(cv1.x, f.y, acc[r].x);
        acc[r].y = fmaf(cv1.y, f.y, acc[r].y);
        acc[r].z = fmaf(cv1.z, f.y, acc[r].z);
        acc[r].w = fmaf(cv1.w, f.y, acc[r].w);
        acc[r].x = fmaf(cv2.x, f.z, acc[r].x);
        acc[r].y = fmaf(cv2.y, f.z, acc[r].y);
        acc[r].z = fmaf(cv2.z, f.z, acc[r].z);
        acc[r].w = fmaf(cv2.w, f.z, acc[r].w);
        acc[r].x = fmaf(cv3.x, f.w, acc[r].x);
        acc[r].y = fmaf(cv3.y, f.w, acc[r].y);
        acc[r].z = fmaf(cv3.z, f.w, acc[r].z);
        acc[r].w = fmaf(cv3.w, f.w, acc[r].w);
      }
    }

    // per-row argmax: within-thread (ascending idx, strict >), cross-lane, cross-wave
#pragma unroll
    for (int r = 0; r < ROWS; ++r) {
      float v = acc[r].x; int c = c0;
      if (acc[r].y > v) { v = acc[r].y; c = c0 + 1; }
      if (acc[r].z > v) { v = acc[r].z; c = c0 + 2; }
      if (acc[r].w > v) { v = acc[r].w; c = c0 + 3; }
#pragma unroll
      for (int off = 32; off > 0; off >>= 1) {
        const float ov = __shfl_xor(v, off);
        const int   oc = __shfl_xor(c, off);
        if (ov > v || (ov == v && oc < c)) { v = ov; c = oc; }
      }
      if (lane == 0) { redv[r][wv] = v; redc[r][wv] = c; }
    }
    __syncthreads();
    if (tid < ROWS) {
      const int r = tid;
      float v = redv[r][0]; int c = redc[r][0];
#pragma unroll
      for (int w = 1; w < 4; ++w) {
        const float ov = redv[r][w]; const int oc = redc[r][w];
        if (ov > v || (ov == v && oc < c)) { v = ov; c = oc; }
      }
      const int gb = b0 + r;
      newlabel[gb] = c;
      if (c != label_bank[ind[gb]]) atomicAdd(count, 1);
    }
  } else {
    // ---- streaming copy of the whole bank; NT stores keep L2/L3 for reads ----
    const int cpy = bid >> 1;            // 0..2047
    const size_t stride = (size_t)GCPY * 256;
    const size_t n4 = (size_t)Lb * D4;
    const vfloat4* __restrict__ src = (const vfloat4*)bank4;
    vfloat4* __restrict__ dst = (vfloat4*)out4;
    size_t i = (size_t)cpy * 256 + tid;
    for (; i + 3 * stride < n4; i += 4 * stride) {
      const vfloat4 a = src[i];
      const vfloat4 b = src[i + stride];
      const vfloat4 c = src[i + 2 * stride];
      const vfloat4 d = src[i + 3 * stride];
      __builtin_nontemporal_store(a, &dst[i]);
      __builtin_nontemporal_store(b, &dst[i + stride]);
      __builtin_nontemporal_store(c, &dst[i + 2 * stride]);
      __builtin_nontemporal_store(d, &dst[i + 3 * stride]);
    }
    for (; i < n4; i += stride) __builtin_nontemporal_store(src[i], &dst[i]);
  }
}

// winner rows from fnew, labels, ratio
__global__ __launch_bounds__(256)
void k_post(const float4* __restrict__ fnew4, const int* __restrict__ ind,
            const int* __restrict__ marker, const int* __restrict__ newlabel,
            const int* __restrict__ label_bank, const int* __restrict__ count,
            float4* __restrict__ out4, float* __restrict__ out_lab,
            float* __restrict__ out_ratio) {
  const int tid = threadIdx.x, lane = tid & 63, wv = tid >> 6;
  const int t = blockIdx.x * 256 + tid;
  const int stride = GPOST * 256;
  for (int i = t; i < Lb; i += stride) {
    const int m = marker[i];
    out_lab[i] = (float)(m >= 0 ? newlabel[m] : label_bank[i]);
  }
  const int w = blockIdx.x * 4 + wv;
  for (int b = w; b < Bb; b += GPOST * 4) {
    const int r = ind[b];
    if (marker[r] == b) out4[(size_t)r * D4 + lane] = fnew4[(size_t)b * D4 + lane];
  }
  if (t == 0) *out_ratio = (float)(*count) / (float)Bb;
}

extern "C" void kernel_launch(void* const* d_in, const int* in_sizes, int n_in,
                              void* d_out, int out_size, void* d_ws, size_t ws_size,
                              hipStream_t stream) {
  const float* bank       = (const float*)d_in[0];
  const int*   label_bank = (const int*)  d_in[1];
  const float* cent       = (const float*)d_in[2];
  const int*   ind        = (const int*)  d_in[3];
  const float* feat       = (const float*)d_in[4];
  float* out = (float*)d_out;

  int*   marker   = (int*)d_ws;                  // [Lb]
  int*   newlabel = marker + Lb;                 // [Bb]
  int*   count    = newlabel + Bb;               // [1]
  float* centT    = (float*)(count + 1);         // [Dm*Cc]  1 MB
  float* fnew     = centT + (size_t)Dm * Cc;     // [Bb*Dm] 16 MB

  float* out_lab   = out + (size_t)Lb * Dm;
  float* out_ratio = out_lab + Lb;

  k_pre <<<GPRE, 256, 0, stream>>>((const float4*)feat, (const float4*)bank, ind,
                                   cent, centT, (float4*)fnew, marker, count);
  k_main<<<GMAIN + GMARK, 256, 0, stream>>>((const float4*)bank, (const float4*)centT,
                                            (const float4*)fnew, ind, label_bank,
                                            marker, newlabel, count, (float4*)out);
  k_post<<<GPOST, 256, 0, stream>>>((const float4*)fnew, ind, marker, newlabel,
                                    label_bank, count, (float4*)out, out_lab, out_ratio);
}

// Round 6
// 281.878 us; speedup vs baseline: 1.8139x; 1.0162x over previous
//
#include <hip/hip_runtime.h>
#include <math.h>

// ODCMemory.update_samples_memory for MI355X (gfx950)
// d_in[0] feature_bank [L,D] f32   d_in[1] label_bank [L] int32
// d_in[2] centroids   [C,D] f32    d_in[3] ind [B] int32
// d_in[4] feature     [B,D] f32
// d_out f32: new_bank [L*D] | new_labels [L] | change_ratio [1]

constexpr int Lb = 500000;
constexpr int Dm = 256;
constexpr int D4 = 64;          // float4 per row
constexpr int Cc = 1024;
constexpr int Bb = 16384;
constexpr float EPSV = 1e-10f;

constexpr int ROWS  = 8;                // batch rows per classify block
constexpr int GCLS  = Bb / ROWS;        // 2048 classify blocks
constexpr int GCPY  = 2048;             // copy blocks
constexpr int GMAIN = GCLS + GCPY;      // 4096, interleaved 1:1 by bid&1
constexpr int GMARK = Bb / 256;         // 64 marking blocks (tail)
constexpr int GPRE  = 1024;
constexpr int GPOST = 1024;

typedef float vfloat4 __attribute__((ext_vector_type(4)));  // native vec for NT stores

__device__ __forceinline__ float wave_sum64(float v) {
#pragma unroll
  for (int off = 32; off > 0; off >>= 1) v += __shfl_xor(v, off);
  return v;
}

// momentum-normalized feature for batch row gb vs bank row bankrow (lane = float4 slice)
__device__ __forceinline__ float4 feat_new_row(const float4* __restrict__ feat4,
                                               const float4* __restrict__ bank4,
                                               int gb, int bankrow, int lane) {
  float4 f = feat4[(size_t)gb * D4 + lane];
  const float ss = wave_sum64(f.x * f.x + f.y * f.y + f.z * f.z + f.w * f.w);
  const float inv1 = 1.0f / (sqrtf(ss) + EPSV);
  const float4 o = bank4[(size_t)bankrow * D4 + lane];
  float4 nw;
  nw.x = 0.5f * o.x + 0.5f * (f.x * inv1);
  nw.y = 0.5f * o.y + 0.5f * (f.y * inv1);
  nw.z = 0.5f * o.z + 0.5f * (f.z * inv1);
  nw.w = 0.5f * o.w + 0.5f * (f.w * inv1);
  const float s2 = wave_sum64(nw.x * nw.x + nw.y * nw.y + nw.z * nw.z + nw.w * nw.w);
  const float inv2 = 1.0f / (sqrtf(s2) + EPSV);
  nw.x *= inv2; nw.y *= inv2; nw.z *= inv2; nw.w *= inv2;
  return nw;
}

// marker clear + count clear + centroid transpose + feat_new precompute
__global__ __launch_bounds__(256)
void k_pre(const float4* __restrict__ feat4, const float4* __restrict__ bank4,
           const int* __restrict__ ind, const float* __restrict__ cent,
           float* __restrict__ centT, float4* __restrict__ fnew4,
           int* __restrict__ marker, int* __restrict__ count) {
  const int tid = threadIdx.x, lane = tid & 63, wv = tid >> 6;
  const int t = blockIdx.x * 256 + tid;
  const int stride = GPRE * 256;
  for (int i = t; i < Lb; i += stride) marker[i] = -1;
  for (int i = t; i < Cc * Dm; i += stride) {
    const int d = i >> 10, c = i & (Cc - 1);
    centT[i] = cent[c * Dm + d];          // centT[d][c]; coalesced write
  }
  if (t == 0) *count = 0;
  const int w = blockIdx.x * 4 + wv;      // 4096 waves, 4 rows each
  for (int b = w; b < Bb; b += GPRE * 4)
    fnew4[(size_t)b * D4 + lane] = feat_new_row(feat4, bank4, b, ind[b], lane);
}

__global__ __launch_bounds__(256, 4)
void k_main(const float4* __restrict__ bank4, const float4* __restrict__ centT4,
            const float4* __restrict__ fnew4, const int* __restrict__ ind,
            const int* __restrict__ label_bank, int* __restrict__ marker,
            int* __restrict__ newlabel, int* __restrict__ count,
            float4* __restrict__ out4) {
  const int tid  = threadIdx.x;
  const int lane = tid & 63;
  const int wv   = tid >> 6;
  const int bid  = blockIdx.x;

  if (bid >= GMAIN) {
    // ---- marking: last-occurrence-wins via atomicMax ----
    const int b = (bid - GMAIN) * 256 + tid;
    if (b < Bb) atomicMax(&marker[ind[b]], b);
    return;
  }

  if ((bid & 1) == 0) {
    // ---- classify: 8 batch rows vs all 1024 centroids; thread owns 4 cents ----
    __shared__ float4 fs[ROWS][D4];      // 8 KB feat tile
    __shared__ float  redv[ROWS][4];
    __shared__ int    redc[ROWS][4];
    const int cls = bid >> 1;            // 0..2047
    const int b0  = cls * ROWS;
    const int c0  = tid * 4;             // this thread's 4 centroids

    for (int k = tid; k < ROWS * D4; k += 256)
      ((float4*)fs)[k] = fnew4[(size_t)b0 * D4 + k];
    __syncthreads();

    float4 acc[ROWS];
#pragma unroll
    for (int r = 0; r < ROWS; ++r) acc[r] = make_float4(0.f, 0.f, 0.f, 0.f);

    const float4* __restrict__ cvp = centT4 + tid;   // centT4[d*256 + tid]

    // software-pipelined: cv holds current d4 group, nv prefetches next
    float4 cv0 = cvp[0 * 256];
    float4 cv1 = cvp[1 * 256];
    float4 cv2 = cvp[2 * 256];
    float4 cv3 = cvp[3 * 256];

    for (int d4 = 0; d4 < D4; ++d4) {
      const int nx = (d4 + 1) & 63;                  // wrap: last prefetch redundant
      const float4 nv0 = cvp[(size_t)(nx * 4 + 0) * 256];
      const float4 nv1 = cvp[(size_t)(nx * 4 + 1) * 256];
      const float4 nv2 = cvp[(size_t)(nx * 4 + 2) * 256];
      const float4 nv3 = cvp[(size_t)(nx * 4 + 3) * 256];

      float4 f[ROWS];
#pragma unroll
      for (int r = 0; r < ROWS; ++r) f[r] = fs[r][d4];   // LDS broadcast, batched

#pragma unroll
      for (int r = 0; r < ROWS; ++r) {
        acc[r].x = fmaf(cv0.x, f[r].x, acc[r].x);
        acc[r].y = fmaf(cv0.y, f[r].x, acc[r].y);
        acc[r].z = fmaf(cv0.z, f[r].x, acc[r].z);
        acc[r].w = fmaf(cv0.w, f[r].x, acc[r].w);
        acc[r].x = fmaf(cv1.x, f[r].y, acc[r].x);
        acc[r].y = fmaf(cv1.y, f[r].y, acc[r].y);
        acc[r].z = fmaf(cv1.z, f[r].y, acc[r].z);
        acc[r].w = fmaf(cv1.w, f[r].y, acc[r].w);
        acc[r].x = fmaf(cv2.x, f[r].z, acc[r].x);
        acc[r].y = fmaf(cv2.y, f[r].z, acc[r].y);
        acc[r].z = fmaf(cv2.z, f[r].z, acc[r].z);
        acc[r].w = fmaf(cv2.w, f[r].z, acc[r].w);
        acc[r].x = fmaf(cv3.x, f[r].w, acc[r].x);
        acc[r].y = fmaf(cv3.y, f[r].w, acc[r].y);
        acc[r].z = fmaf(cv3.z, f[r].w, acc[r].z);
        acc[r].w = fmaf(cv3.w, f[r].w, acc[r].w);
      }
      cv0 = nv0; cv1 = nv1; cv2 = nv2; cv3 = nv3;
    }

    // per-row argmax: within-thread (ascending idx, strict >), cross-lane, cross-wave
#pragma unroll
    for (int r = 0; r < ROWS; ++r) {
      float v = acc[r].x; int c = c0;
      if (acc[r].y > v) { v = acc[r].y; c = c0 + 1; }
      if (acc[r].z > v) { v = acc[r].z; c = c0 + 2; }
      if (acc[r].w > v) { v = acc[r].w; c = c0 + 3; }
#pragma unroll
      for (int off = 32; off > 0; off >>= 1) {
        const float ov = __shfl_xor(v, off);
        const int   oc = __shfl_xor(c, off);
        if (ov > v || (ov == v && oc < c)) { v = ov; c = oc; }
      }
      if (lane == 0) { redv[r][wv] = v; redc[r][wv] = c; }
    }
    __syncthreads();
    if (tid < ROWS) {
      const int r = tid;
      float v = redv[r][0]; int c = redc[r][0];
#pragma unroll
      for (int w = 1; w < 4; ++w) {
        const float ov = redv[r][w]; const int oc = redc[r][w];
        if (ov > v || (ov == v && oc < c)) { v = ov; c = oc; }
      }
      const int gb = b0 + r;
      newlabel[gb] = c;
      if (c != label_bank[ind[gb]]) atomicAdd(count, 1);
    }
  } else {
    // ---- streaming copy of the whole bank; NT stores keep L2/L3 for reads ----
    const int cpy = bid >> 1;            // 0..2047
    const size_t stride = (size_t)GCPY * 256;
    const size_t n4 = (size_t)Lb * D4;
    const vfloat4* __restrict__ src = (const vfloat4*)bank4;
    vfloat4* __restrict__ dst = (vfloat4*)out4;
    size_t i = (size_t)cpy * 256 + tid;
    for (; i + 3 * stride < n4; i += 4 * stride) {
      const vfloat4 a = src[i];
      const vfloat4 b = src[i + stride];
      const vfloat4 c = src[i + 2 * stride];
      const vfloat4 d = src[i + 3 * stride];
      __builtin_nontemporal_store(a, &dst[i]);
      __builtin_nontemporal_store(b, &dst[i + stride]);
      __builtin_nontemporal_store(c, &dst[i + 2 * stride]);
      __builtin_nontemporal_store(d, &dst[i + 3 * stride]);
    }
    for (; i < n4; i += stride) __builtin_nontemporal_store(src[i], &dst[i]);
  }
}

// winner rows from fnew, labels, ratio
__global__ __launch_bounds__(256)
void k_post(const float4* __restrict__ fnew4, const int* __restrict__ ind,
            const int* __restrict__ marker, const int* __restrict__ newlabel,
            const int* __restrict__ label_bank, const int* __restrict__ count,
            float4* __restrict__ out4, float* __restrict__ out_lab,
            float* __restrict__ out_ratio) {
  const int tid = threadIdx.x, lane = tid & 63, wv = tid >> 6;
  const int t = blockIdx.x * 256 + tid;
  const int stride = GPOST * 256;
  for (int i = t; i < Lb; i += stride) {
    const int m = marker[i];
    out_lab[i] = (float)(m >= 0 ? newlabel[m] : label_bank[i]);
  }
  const int w = blockIdx.x * 4 + wv;
  for (int b = w; b < Bb; b += GPOST * 4) {
    const int r = ind[b];
    if (marker[r] == b) out4[(size_t)r * D4 + lane] = fnew4[(size_t)b * D4 + lane];
  }
  if (t == 0) *out_ratio = (float)(*count) / (float)Bb;
}

extern "C" void kernel_launch(void* const* d_in, const int* in_sizes, int n_in,
                              void* d_out, int out_size, void* d_ws, size_t ws_size,
                              hipStream_t stream) {
  const float* bank       = (const float*)d_in[0];
  const int*   label_bank = (const int*)  d_in[1];
  const float* cent       = (const float*)d_in[2];
  const int*   ind        = (const int*)  d_in[3];
  const float* feat       = (const float*)d_in[4];
  float* out = (float*)d_out;

  int*   marker   = (int*)d_ws;                  // [Lb]
  int*   newlabel = marker + Lb;                 // [Bb]
  int*   count    = newlabel + Bb;               // [1]
  float* centT    = (float*)(count + 1);         // [Dm*Cc]  1 MB
  float* fnew     = centT + (size_t)Dm * Cc;     // [Bb*Dm] 16 MB

  float* out_lab   = out + (size_t)Lb * Dm;
  float* out_ratio = out_lab + Lb;

  k_pre <<<GPRE, 256, 0, stream>>>((const float4*)feat, (const float4*)bank, ind,
                                   cent, centT, (float4*)fnew, marker, count);
  k_main<<<GMAIN + GMARK, 256, 0, stream>>>((const float4*)bank, (const float4*)centT,
                                            (const float4*)fnew, ind, label_bank,
                                            marker, newlabel, count, (float4*)out);
  k_post<<<GPOST, 256, 0, stream>>>((const float4*)fnew, ind, marker, newlabel,
                                    label_bank, count, (float4*)out, out_lab, out_ratio);
}